// Round 9
// baseline (337.016 us; speedup 1.0000x reference)
//
#include <hip/hip_runtime.h>
#include <hip/hip_cooperative_groups.h>
#include <math.h>

namespace cg = cooperative_groups;

#define H 768
#define L 256
#define NB 4
#define NL 13

typedef _Float16 h2 __attribute__((ext_vector_type(2)));
typedef _Float16 half8 __attribute__((ext_vector_type(8)));
typedef float f32x4 __attribute__((ext_vector_type(4)));

// Packed-fp16 GELU: erf(x/sqrt2) ~= xc*P(v), v = (xc*xc)/8, xc = clamp(x,+-3.75).
__device__ inline h2 gelu_pk(h2 x) {
    const _Float16 kC = (_Float16)3.75f;
    h2 hi = {kC, kC}, lo = {(_Float16)-3.75f, (_Float16)-3.75f};
    h2 xc = __builtin_elementwise_min(__builtin_elementwise_max(x, lo), hi);
    h2 u = xc * xc;
    const _Float16 kE = (_Float16)0.125f;
    h2 ve = {kE, kE};
    h2 v = u * ve;
    const _Float16 d4v = (_Float16)0.0832840f,  d3v = (_Float16)-0.4335206f;
    const _Float16 d2v = (_Float16)0.8960128f,  d1v = (_Float16)-0.9876456f;
    const _Float16 d0v = (_Float16)0.7946463f;
    h2 d4 = {d4v, d4v}, d3 = {d3v, d3v}, d2 = {d2v, d2v}, d1 = {d1v, d1v}, d0 = {d0v, d0v};
    h2 p = v * (v * (v * (v * d4 + d3) + d2) + d1) + d0;   // v_pk_fma_f16 chain
    h2 t = xc * p;
    const _Float16 kH = (_Float16)0.5f;
    h2 halfv = {kH, kH};
    h2 hx = x * halfv;
    return hx * t + hx;
}

// ---------------- Cooperative mono-kernel ------------------------------------
// grid 1024 x 256 (4 blocks/CU co-resident).
// Phase A: fragment prep (Afrag / Bfrag1 / Bfrag2), flat work-indexed.
// Phase B: stage-1 GEMM as 3072 wave-jobs (1 m-tile x 2 n-tiles each).
// Phase C: span = gelu + W2 MFMA; 2 logical R8-span-blocks per physical block.
__global__ __launch_bounds__(256, 4) void mono_kernel(
    const float* __restrict__ X, const float* __restrict__ W1,
    const float* __restrict__ b1, const float* __restrict__ W2,
    const float* __restrict__ b2,
    _Float16* __restrict__ Afrag, _Float16* __restrict__ Bfrag1,
    _Float16* __restrict__ Bfrag2,
    _Float16* __restrict__ Pxs2, _Float16* __restrict__ Pxe,
    float* __restrict__ out)
{
    cg::grid_group grid = cg::this_grid();
    const int blk = blockIdx.x;
    const int tid = threadIdx.x;
    const int lane = tid & 63;
    const int wave = tid >> 6;
    const int ln = lane & 15, quad = lane >> 4;

    __shared__ unsigned int xsf[2 * H / 2];   // phase C: two i-rows of fp16 pairs

    // ================= Phase A: prep =================
    {
        int t = blk * 256 + tid;                 // [0, 262144)
        if (t < 98304) {
            int l = t & 63;
            int g = t >> 6;                      // [0, 1536)
            int kb = g % 24, mt = g / 24;
            int m = mt * 16 + (l & 15);
            int k0 = kb * 32 + (l >> 4) * 8;
            const float* px = X + (size_t)m * H + k0;
            float4 a = *(const float4*)px;
            float4 c = *(const float4*)(px + 4);
            half8 o = { (_Float16)a.x, (_Float16)a.y, (_Float16)a.z, (_Float16)a.w,
                        (_Float16)c.x, (_Float16)c.y, (_Float16)c.z, (_Float16)c.w };
            *(half8*)(Afrag + (size_t)t * 8) = o;
        } else if (t < 245760) {
            int t2 = t - 98304;                  // [0, 147456)
            int l = t2 & 63;
            int g = t2 >> 6;                     // [0, 2304)
            int kb = g % 24, ntg = g / 24;       // ntg in [0,96)
            int np = ntg * 16 + (l & 15);        // n' in [0,1536)
            int k0 = kb * 32 + (l >> 4) * 8;
            const float* Wb = W1 + ((np >= H) ? (size_t)H * H : 0);
            int c = np - ((np >= H) ? H : 0);
            half8 o;
            #pragma unroll
            for (int u = 0; u < 8; ++u)
                o[u] = (_Float16)Wb[(size_t)(k0 + u) * H + c];
            *(half8*)(Bfrag1 + (size_t)t2 * 8) = o;
        } else if (t < 258048) {
            int idx = t - 245760;                // [0, 12288)
            int u = idx & 7;
            int l = (idx >> 3) & 63;
            int kb = idx >> 9;
            int k = kb * 32 + ((l >> 4) << 3) + u;
            int n = l & 15;
            float v = (n < NL) ? W2[(size_t)k * NL + n] : 0.f;
            Bfrag2[idx] = (_Float16)v;
        }
    }
    grid.sync();

    // ================= Phase B: stage-1 GEMM =================
    {
        int wj = blk * 4 + wave;                 // global wave id
        if (wj < 3072) {
            int mt = wj / 48;                    // [0,64)
            int p  = wj % 48;                    // n-tile pair; p<24 -> Pxs side
            int ntg0 = p * 2;

            const half8* pa  = (const half8*)(Afrag + (((size_t)mt * 24) * 64 + lane) * 8);
            const half8* pb0 = (const half8*)(Bfrag1 + (((size_t)ntg0 * 24) * 64 + lane) * 8);
            const half8* pb1 = pb0 + (size_t)24 * 64;

            f32x4 acc[2] = {};
            #pragma unroll 4
            for (int kb = 0; kb < 24; ++kb) {
                half8 a  = pa[kb * 64];
                half8 b0 = pb0[kb * 64];
                half8 b1v = pb1[kb * 64];
                acc[0] = __builtin_amdgcn_mfma_f32_16x16x32_f16(a, b0, acc[0], 0, 0, 0);
                acc[1] = __builtin_amdgcn_mfma_f32_16x16x32_f16(a, b1v, acc[1], 0, 0, 0);
            }

            if (p < 24) {
                #pragma unroll
                for (int nt = 0; nt < 2; ++nt) {
                    int np = (ntg0 + nt) * 16 + ln;
                    float bv = b1[np];
                    #pragma unroll
                    for (int r = 0; r < 4; ++r) {
                        int m = mt * 16 + quad * 4 + r;
                        Pxs2[(size_t)m * H + np] = (_Float16)(acc[nt][r] + bv);
                    }
                }
            } else {
                #pragma unroll
                for (int nt = 0; nt < 2; ++nt) {
                    int np = (ntg0 + nt) * 16 + ln - H;
                    #pragma unroll
                    for (int r = 0; r < 4; ++r) {
                        int m = mt * 16 + quad * 4 + r;
                        Pxe[(size_t)m * H + np] = (_Float16)acc[nt][r];
                    }
                }
            }
        }
    }
    grid.sync();

    // ================= Phase C: span =================
    {
        const int ip = blk >> 1;                 // [0,512)
        const int bi0 = ip * 2;                  // b*L + i pair start
        const int b = bi0 >> 8;
        const unsigned int* xsrc = (const unsigned int*)(Pxs2 + (size_t)bi0 * H);
        for (int t = tid; t < H; t += 256) xsf[t] = xsrc[t];
        __syncthreads();

        const int n = ln;
        const int jq0 = (blk & 1) * 2;
        const half8* bptr = (const half8*)(Bfrag2 + (size_t)lane * 8);
        const float b2v = (n < NL) ? b2[n] : 0.f;

        #pragma unroll
        for (int rep = 0; rep < 2; ++rep) {
            const int jq = jq0 + rep;
            const int j_load = jq * 64 + wave * 16 + n;
            const _Float16* xerow = Pxe + (size_t)(b * L + j_load) * H + quad * 8;

            f32x4 acc[2] = {};
            for (int kb = 0; kb < H / 32; ++kb) {
                half8 bfrag = bptr[kb * 64];
                uint4 xev = *(const uint4*)(xerow + kb * 32);
                h2 xep[4] = { __builtin_bit_cast(h2, xev.x), __builtin_bit_cast(h2, xev.y),
                              __builtin_bit_cast(h2, xev.z), __builtin_bit_cast(h2, xev.w) };
                const int xo = kb * 16 + quad * 4;

                #pragma unroll
                for (int i01 = 0; i01 < 2; ++i01) {
                    uint4 xsd = *(const uint4*)&xsf[i01 * (H / 2) + xo];
                    h2 xsp[4] = { __builtin_bit_cast(h2, xsd.x), __builtin_bit_cast(h2, xsd.y),
                                  __builtin_bit_cast(h2, xsd.z), __builtin_bit_cast(h2, xsd.w) };
                    unsigned int pk[4];
                    #pragma unroll
                    for (int pp = 0; pp < 4; ++pp) {
                        h2 g = gelu_pk(xsp[pp] + xep[pp]);
                        pk[pp] = __builtin_bit_cast(unsigned int, g);
                    }
                    uint4 pk4 = {pk[0], pk[1], pk[2], pk[3]};
                    half8 afrag = __builtin_bit_cast(half8, pk4);
                    acc[i01] = __builtin_amdgcn_mfma_f32_16x16x32_f16(afrag, bfrag, acc[i01], 0, 0, 0);
                }
            }

            if (n < NL) {
                #pragma unroll
                for (int i01 = 0; i01 < 2; ++i01)
                    #pragma unroll
                    for (int r = 0; r < 4; ++r) {
                        int j = jq * 64 + wave * 16 + quad * 4 + r;
                        out[((size_t)(bi0 + i01) * L + j) * NL + n] = acc[i01][r] + b2v;
                    }
            }
        }
    }
}

// ---------------- Launch ------------------------------------------------------
extern "C" void kernel_launch(void* const* d_in, const int* in_sizes, int n_in,
                              void* d_out, int out_size, void* d_ws, size_t ws_size,
                              hipStream_t stream)
{
    (void)in_sizes; (void)n_in; (void)out_size; (void)ws_size;
    const float* X  = (const float*)d_in[0];
    const float* W1 = (const float*)d_in[1];
    const float* b1 = (const float*)d_in[2];
    const float* W2 = (const float*)d_in[3];
    const float* b2 = (const float*)d_in[4];
    float* out = (float*)d_out;

    char* ws = (char*)d_ws;
    _Float16* Pxs2   = (_Float16*)ws;                          // 1.5 MB
    _Float16* Pxe    = Pxs2 + (size_t)NB * L * H;              // 1.5 MB
    _Float16* Afrag  = Pxe + (size_t)NB * L * H;               // 1.5 MB
    _Float16* Bfrag1 = Afrag + (size_t)NB * L * H;             // 2.25 MB
    _Float16* Bfrag2 = Bfrag1 + (size_t)2 * H * H;             // 24 KB

    void* args[] = { (void*)&X, (void*)&W1, (void*)&b1, (void*)&W2, (void*)&b2,
                     (void*)&Afrag, (void*)&Bfrag1, (void*)&Bfrag2,
                     (void*)&Pxs2, (void*)&Pxe, (void*)&out };
    hipLaunchCooperativeKernel((const void*)mono_kernel, dim3(1024), dim3(256),
                               args, 0, stream);
}

// Round 11
// 123.671 us; speedup vs baseline: 2.7251x; 2.7251x over previous
//
#include <hip/hip_runtime.h>
#include <math.h>

#define H 768
#define L 256
#define NB 4
#define NL 13

typedef _Float16 h2 __attribute__((ext_vector_type(2)));
typedef _Float16 half8 __attribute__((ext_vector_type(8)));
typedef float f32x4 __attribute__((ext_vector_type(4)));

// Packed-fp16 GELU (h2 ext-vector -> v_pk_* codegen, verified compiles R5-R8).
// erf(x/sqrt2) ~= xc*P(v), v=(xc*xc)/8, xc=clamp(x,+-3.75); coeffs fp16-normal.
__device__ inline h2 gelu_pk(h2 x) {
    const _Float16 kC = (_Float16)3.75f;
    h2 hi = {kC, kC}, lo = {(_Float16)-3.75f, (_Float16)-3.75f};
    h2 xc = __builtin_elementwise_min(__builtin_elementwise_max(x, lo), hi);
    h2 u = xc * xc;
    const _Float16 kE = (_Float16)0.125f;
    h2 ve = {kE, kE};
    h2 v = u * ve;
    const _Float16 d4v = (_Float16)0.0832840f,  d3v = (_Float16)-0.4335206f;
    const _Float16 d2v = (_Float16)0.8960128f,  d1v = (_Float16)-0.9876456f;
    const _Float16 d0v = (_Float16)0.7946463f;
    h2 d4 = {d4v, d4v}, d3 = {d3v, d3v}, d2 = {d2v, d2v}, d1 = {d1v, d1v}, d0 = {d0v, d0v};
    h2 p = v * (v * (v * (v * d4 + d3) + d2) + d1) + d0;   // v_pk_fma_f16 chain
    h2 t = xc * p;
    const _Float16 kH = (_Float16)0.5f;
    h2 halfv = {kH, kH};
    h2 hx = x * halfv;
    return hx * t + hx;
}

// ---------------- Prep: direct global->global fragment packing (R8) ----------
__global__ __launch_bounds__(256) void prep_kernel(
    const float* __restrict__ X, const float* __restrict__ W1,
    const float* __restrict__ W2,
    _Float16* __restrict__ Afrag, _Float16* __restrict__ Bfrag1,
    _Float16* __restrict__ Bfrag2)
{
    const int blk = blockIdx.x;
    const int tid = threadIdx.x;

    if (blk < 384) {
        int t = blk * 256 + tid;                 // [0, 98304)
        int lane = t & 63;
        int g = t >> 6;                          // [0, 1536)
        int kb = g % 24, mt = g / 24;
        int m = mt * 16 + (lane & 15);
        int k0 = kb * 32 + (lane >> 4) * 8;
        const float* px = X + (size_t)m * H + k0;
        float4 a = *(const float4*)px;
        float4 b = *(const float4*)(px + 4);
        half8 o = { (_Float16)a.x, (_Float16)a.y, (_Float16)a.z, (_Float16)a.w,
                    (_Float16)b.x, (_Float16)b.y, (_Float16)b.z, (_Float16)b.w };
        *(half8*)(Afrag + (size_t)t * 8) = o;
    } else if (blk < 960) {
        int t = (blk - 384) * 256 + tid;         // [0, 147456)
        int lane = t & 63;
        int g = t >> 6;                          // [0, 2304)
        int kb = g % 24, ntg = g / 24;           // ntg in [0,96)
        int np = ntg * 16 + (lane & 15);         // n' in [0,1536)
        int k0 = kb * 32 + (lane >> 4) * 8;
        const float* Wb = W1 + ((np >= H) ? (size_t)H * H : 0);
        int c = np - ((np >= H) ? H : 0);
        half8 o;
        #pragma unroll
        for (int u = 0; u < 8; ++u)
            o[u] = (_Float16)Wb[(size_t)(k0 + u) * H + c];
        *(half8*)(Bfrag1 + (size_t)t * 8) = o;
    } else {
        int base = (blk - 960) * 768 + tid;
        #pragma unroll
        for (int r = 0; r < 3; ++r) {
            int idx = base + r * 256;            // < 12288
            int u = idx & 7;
            int lane = (idx >> 3) & 63;
            int kb = idx >> 9;
            int k = kb * 32 + ((lane >> 4) << 3) + u;
            int n = lane & 15;
            float v = (n < NL) ? W2[(size_t)k * NL + n] : 0.f;
            Bfrag2[idx] = (_Float16)v;
        }
    }
}

// ---------------- Stage 1: MFMA GEMM, fragment-direct, no LDS (R8) -----------
__global__ __launch_bounds__(256) void gemm_mfma(
    const _Float16* __restrict__ Afrag, const _Float16* __restrict__ Bfrag1,
    const float* __restrict__ b1, _Float16* __restrict__ Pxs2,
    _Float16* __restrict__ Pxe)
{
    const int tid = threadIdx.x;
    const int w = tid >> 6, lane = tid & 63;
    const int ln = lane & 15, quad = lane >> 4;
    const int m0 = blockIdx.x * 64 + (w & 1) * 32;
    const int n0g = blockIdx.y * 64 + (w >> 1) * 32;
    const int mt0 = m0 >> 4, ntg0 = n0g >> 4;

    const half8* pa0 = (const half8*)(Afrag + (((size_t)mt0 * 24) * 64 + lane) * 8);
    const half8* pa1 = (const half8*)(Afrag + ((((size_t)mt0 + 1) * 24) * 64 + lane) * 8);
    const half8* pb0 = (const half8*)(Bfrag1 + (((size_t)ntg0 * 24) * 64 + lane) * 8);
    const half8* pb1 = (const half8*)(Bfrag1 + ((((size_t)ntg0 + 1) * 24) * 64 + lane) * 8);

    f32x4 acc[2][2] = {};
    #pragma unroll 4
    for (int kb = 0; kb < 24; ++kb) {
        half8 a0 = pa0[kb * 64];
        half8 a1 = pa1[kb * 64];
        half8 b0 = pb0[kb * 64];
        half8 b1v = pb1[kb * 64];
        acc[0][0] = __builtin_amdgcn_mfma_f32_16x16x32_f16(a0, b0, acc[0][0], 0, 0, 0);
        acc[0][1] = __builtin_amdgcn_mfma_f32_16x16x32_f16(a0, b1v, acc[0][1], 0, 0, 0);
        acc[1][0] = __builtin_amdgcn_mfma_f32_16x16x32_f16(a1, b0, acc[1][0], 0, 0, 0);
        acc[1][1] = __builtin_amdgcn_mfma_f32_16x16x32_f16(a1, b1v, acc[1][1], 0, 0, 0);
    }

    if (n0g < H) {
        float bv[2] = { b1[n0g + ln], b1[n0g + 16 + ln] };
        #pragma unroll
        for (int mt = 0; mt < 2; ++mt)
            #pragma unroll
            for (int nt = 0; nt < 2; ++nt) {
                int n = n0g + nt * 16 + ln;
                #pragma unroll
                for (int r = 0; r < 4; ++r) {
                    int m = m0 + mt * 16 + quad * 4 + r;
                    Pxs2[(size_t)m * H + n] = (_Float16)(acc[mt][nt][r] + bv[nt]);
                }
            }
    } else {
        #pragma unroll
        for (int mt = 0; mt < 2; ++mt)
            #pragma unroll
            for (int nt = 0; nt < 2; ++nt) {
                int n = n0g - H + nt * 16 + ln;
                #pragma unroll
                for (int r = 0; r < 4; ++r) {
                    int m = m0 + mt * 16 + quad * 4 + r;
                    Pxe[(size_t)m * H + n] = (_Float16)acc[mt][nt][r];
                }
            }
    }
}

// ---------------- Stage 2: span v4 — 4 i-rows share each xe load -------------
// grid 1024: block = (iquad, jq). Each wave: 16 j (one m-tile) x 4 i.
// Per kb: 1 bfrag + 1 xe load feed 4 gelu+MFMA streams (independent acc chains).
__global__ __launch_bounds__(256, 4) void span_mfma_kernel(
    const _Float16* __restrict__ Pxs2, const _Float16* __restrict__ Pxe,
    const _Float16* __restrict__ Bfrag2, const float* __restrict__ b2,
    float* __restrict__ out)
{
    __shared__ unsigned int xsf[4 * H / 2];   // four i-rows of fp16 pairs (6 KB)
    const int ip = blockIdx.x >> 2;           // 0..255
    const int jq = blockIdx.x & 3;
    const int bi0 = ip * 4;                   // b*L + i (quad start; same b)
    const int b = bi0 >> 8;
    const int tid = threadIdx.x;

    const unsigned int* xsrc = (const unsigned int*)(Pxs2 + (size_t)bi0 * H);
    #pragma unroll
    for (int t = 0; t < 6; ++t) xsf[t * 256 + tid] = xsrc[t * 256 + tid];

    const int wave = tid >> 6;
    const int lane = tid & 63;
    const int n = lane & 15;
    const int quad = lane >> 4;
    const int j_load = jq * 64 + wave * 16 + n;       // A-frag row m = lane&15

    const _Float16* xerow = Pxe + (size_t)(b * L + j_load) * H + quad * 8;
    const half8* bptr = (const half8*)(Bfrag2 + (size_t)lane * 8);

    f32x4 acc[4] = {};
    __syncthreads();

    for (int kb = 0; kb < H / 32; ++kb) {
        half8 bfrag = bptr[kb * 64];
        uint4 xev = *(const uint4*)(xerow + kb * 32);
        h2 xep[4] = { __builtin_bit_cast(h2, xev.x), __builtin_bit_cast(h2, xev.y),
                      __builtin_bit_cast(h2, xev.z), __builtin_bit_cast(h2, xev.w) };
        const int xo = kb * 16 + quad * 4;            // uint index of lane's 8 fp16

        #pragma unroll
        for (int i01 = 0; i01 < 4; ++i01) {
            uint4 xsd = *(const uint4*)&xsf[i01 * (H / 2) + xo];
            h2 xsp[4] = { __builtin_bit_cast(h2, xsd.x), __builtin_bit_cast(h2, xsd.y),
                          __builtin_bit_cast(h2, xsd.z), __builtin_bit_cast(h2, xsd.w) };
            unsigned int pk[4];
            #pragma unroll
            for (int p = 0; p < 4; ++p) {
                h2 g = gelu_pk(xsp[p] + xep[p]);
                pk[p] = __builtin_bit_cast(unsigned int, g);
            }
            uint4 pk4 = {pk[0], pk[1], pk[2], pk[3]};
            half8 afrag = __builtin_bit_cast(half8, pk4);
            acc[i01] = __builtin_amdgcn_mfma_f32_16x16x32_f16(afrag, bfrag, acc[i01], 0, 0, 0);
        }
    }

    // C/D: col = lane&15 = label n, row = quad*4 + r = j-offset in the m-tile
    if (n < NL) {
        float b2v = b2[n];
        #pragma unroll
        for (int i01 = 0; i01 < 4; ++i01)
            #pragma unroll
            for (int r = 0; r < 4; ++r) {
                int j = jq * 64 + wave * 16 + quad * 4 + r;
                out[((size_t)(bi0 + i01) * L + j) * NL + n] = acc[i01][r] + b2v;
            }
    }
}

// ---------------- Launch ------------------------------------------------------
extern "C" void kernel_launch(void* const* d_in, const int* in_sizes, int n_in,
                              void* d_out, int out_size, void* d_ws, size_t ws_size,
                              hipStream_t stream)
{
    (void)in_sizes; (void)n_in; (void)out_size; (void)ws_size;
    const float* X  = (const float*)d_in[0];
    const float* W1 = (const float*)d_in[1];
    const float* b1 = (const float*)d_in[2];
    const float* W2 = (const float*)d_in[3];
    const float* b2 = (const float*)d_in[4];
    float* out = (float*)d_out;

    char* ws = (char*)d_ws;
    _Float16* Pxs2   = (_Float16*)ws;                          // 1.5 MB
    _Float16* Pxe    = Pxs2 + (size_t)NB * L * H;              // 1.5 MB
    _Float16* Afrag  = Pxe + (size_t)NB * L * H;               // 1.5 MB
    _Float16* Bfrag1 = Afrag + (size_t)NB * L * H;             // 2.25 MB
    _Float16* Bfrag2 = Bfrag1 + (size_t)2 * H * H;             // 24 KB

    prep_kernel<<<976, 256, 0, stream>>>(X, W1, W2, Afrag, Bfrag1, Bfrag2);
    gemm_mfma<<<dim3(16, 24), 256, 0, stream>>>(Afrag, Bfrag1, b1, Pxs2, Pxe);
    span_mfma_kernel<<<NB * L, 256, 0, stream>>>(Pxs2, Pxe, Bfrag2, b2, out);
}